// Round 10
// baseline (81.241 us; speedup 1.0000x reference)
//
#include <hip/hip_runtime.h>
#include <hip/hip_bf16.h>

// InfoNCE loss, N=4096, D=256, tau=0.5.
// loss = (1/2n)[ sum_r log(sum_{k!=r} exp(2*Z_r.Z_k)) - 2*sum_i 2*(xn_i.yn_i) ]
// Z = concat(xn, yn) row-normalized; scores in [-2,2] -> no running max needed.
// 2/tau*log2(e) folded into A-side bf16 fragments; epilogue = exp2 + add.
//
// R10: diagnosis of the flat ~47us across R4/R7/R9: combined VGPR+AGPR > 128
// (unified file on gfx950) capped occupancy at 2 waves/SIMD -- every R=2
// variant ran at half of R3's wave-parallelism. Fix: __launch_bounds__(512,4)
// forces combined <=128 (4 waves/SIMD), and the tile is a straight-line
// 8-batch pipeline: issue next 2-frag B-batch (2 ds_read_b128) BEFORE each
// 4-MFMA cluster so DS latency hides under MFMA within each wave. Ring-4 LDS
// + counted vmcnt (R9) kept; setprio around MFMA clusters (T5).

#define NROWS 8192
#define DDIM  256
#define BM    256        // rows per block = 8 waves * 32 rows
#define BN    32         // cols per LDS tile (16 KB)
#define COLSPLIT 16      // grid = 32 * 16 = 512 blocks = 2/CU
#define COLS_PER (NROWS / COLSPLIT)   // 512
#define NT (COLS_PER / BN)            // 16 tiles

typedef __attribute__((ext_vector_type(8))) __bf16 bf16x8_t;
typedef __attribute__((ext_vector_type(4))) float  f32x4_t;

typedef __attribute__((address_space(1))) const void* as1_cvp;
typedef __attribute__((address_space(3))) void*       as3_vp;

#if __has_builtin(__builtin_amdgcn_exp2f)
#define EXP2F __builtin_amdgcn_exp2f
#else
#define EXP2F exp2f
#endif

#define TWO_LOG2E 2.8853900817779268f

// ---- K1: normalize rows + per-pair diag dot + zero rowsum ----
__global__ __launch_bounds__(256) void normalize_diag_kernel(
    const float* __restrict__ x, const float* __restrict__ y,
    __hip_bfloat16* __restrict__ zb, float* __restrict__ rowdiag,
    float* __restrict__ rowsum) {
  const int g = blockIdx.x * 256 + threadIdx.x;
  if (g < NROWS) rowsum[g] = 0.f;

  const int w = threadIdx.x >> 6, lane = threadIdx.x & 63;
  const int i = blockIdx.x * 4 + w;           // 0..4095
  const float4 xv = ((const float4*)(x + (size_t)i * DDIM))[lane];
  const float4 yv = ((const float4*)(y + (size_t)i * DDIM))[lane];
  float ssx = xv.x * xv.x + xv.y * xv.y + xv.z * xv.z + xv.w * xv.w;
  float ssy = yv.x * yv.x + yv.y * yv.y + yv.z * yv.z + yv.w * yv.w;
  float sxy = xv.x * yv.x + xv.y * yv.y + xv.z * yv.z + xv.w * yv.w;
  #pragma unroll
  for (int off = 32; off > 0; off >>= 1) {
    ssx += __shfl_xor(ssx, off, 64);
    ssy += __shfl_xor(ssy, off, 64);
    sxy += __shfl_xor(sxy, off, 64);
  }
  const float sclx = 1.0f / fmaxf(sqrtf(ssx), 1e-8f);
  const float scly = 1.0f / fmaxf(sqrtf(ssy), 1e-8f);
  __hip_bfloat16 px[4], py[4];
  px[0] = __float2bfloat16(xv.x * sclx); px[1] = __float2bfloat16(xv.y * sclx);
  px[2] = __float2bfloat16(xv.z * sclx); px[3] = __float2bfloat16(xv.w * sclx);
  py[0] = __float2bfloat16(yv.x * scly); py[1] = __float2bfloat16(yv.y * scly);
  py[2] = __float2bfloat16(yv.z * scly); py[3] = __float2bfloat16(yv.w * scly);
  *(short4*)(zb + (size_t)i * DDIM + lane * 4)            = *(short4*)px;
  *(short4*)(zb + (size_t)(i + 4096) * DDIM + lane * 4)   = *(short4*)py;
  if (lane == 0) rowdiag[i] = 2.0f * sxy * sclx * scly;   // target score (f32)
}

// ---- K2: fused Gram + per-row sum of exp (reg-pipelined, occupancy-forced) --
__global__ __launch_bounds__(512, 4) void gram_lse_kernel(
    const __hip_bfloat16* __restrict__ zbh, float* __restrict__ rowsum) {
  __shared__ short smem[4][BN * DDIM];  // 4 x 16 KB ring = exactly 64 KB

  const short* zs = (const short*)zbh;
  const char* zbytes = (const char*)zs;
  const int tid  = threadIdx.x;
  const int w    = tid >> 6;    // 0..7
  const int lane = tid & 63;
  const int lhi  = lane >> 4;   // 0..3
  const int llo  = lane & 15;   // 0..15
  const int i0 = (blockIdx.x >> 4) * BM;            // row-tile base (32 tiles)
  const int c0 = (blockIdx.x & 15) * COLS_PER;      // column-range base
  const bool has_diag = ((blockIdx.x >> 5) == (blockIdx.x & 15));

  // Two A-fragment sets (rows arow0, arow0+16), full K=256, pre-scaled by
  // bf16(2*log2e) so MFMA yields score*log2(e) directly. 64 VGPR.
  const int arow0 = i0 + w * 32 + llo;
  const float TBF = __bfloat162float(__float2bfloat16(TWO_LOG2E));
  bf16x8_t afa[8], afb[8];
  #pragma unroll
  for (int ks = 0; ks < 8; ++ks) {
    afa[ks] = *(const bf16x8_t*)(zs + (size_t)arow0 * DDIM + ks * 32 + lhi * 8);
    afb[ks] = *(const bf16x8_t*)(zs + (size_t)(arow0 + 16) * DDIM + ks * 32 + lhi * 8);
    #pragma unroll
    for (int e = 0; e < 8; ++e) {
      afa[ks][e] = (__bf16)((float)afa[ks][e] * TBF);
      afb[ks][e] = (__bf16)((float)afb[ks][e] * TBF);
    }
  }

  // Staging: 2 gld_lds per thread per 16 KB tile. Linear LDS dest; XOR-swizzle
  // on the global source: lds[cr*512 + slot*16] = row(cb+cr) slot (slot^cr).
  int soff[2], loff[2];
  #pragma unroll
  for (int it = 0; it < 2; ++it) {
    const int o    = it * 8192 + tid * 16;
    const int cr   = o >> 9;            // 0..31
    const int slot = (o >> 4) & 31;
    soff[it] = cr * 512 + ((slot ^ cr) << 4);
    loff[it] = it * 8192 + w * 1024;    // wave-uniform dest base
  }

#define STAGE1(buf_, ct_, it_) do {                                           \
    const size_t cbase_ = (size_t)(c0 + (ct_) * BN) * 512;                    \
    __builtin_amdgcn_global_load_lds(                                         \
        (as1_cvp)(zbytes + cbase_ + (size_t)soff[it_]),                       \
        (as3_vp)((char*)smem[buf_] + loff[it_]), 16, 0, 0);                   \
  } while (0)

  float racc0[4] = {0.f, 0.f, 0.f, 0.f};
  float racc1[4] = {0.f, 0.f, 0.f, 0.f};
  f32x4_t acc0 = {0.f, 0.f, 0.f, 0.f};
  f32x4_t acc1 = {0.f, 0.f, 0.f, 0.f};
  const int gr0 = i0 + w * 32 + lhi * 4;   // C/D row = (lane>>4)*4 + j
  const int gr1 = gr0 + 16;

  // B-register banks: 2 frags each (8 VGPR/bank, 16 total live).
  bf16x8_t u0, u1, v0, v1;

#define LDB2(D0, D1, ntv, kk) do {                                            \
    const int cr_ = (ntv) * 16 + llo;                                         \
    const char* rp_ = (const char*)bufp + cr_ * 512;                          \
    D0 = *(const bf16x8_t*)(rp_ + (((((kk)    ) * 4 + lhi) ^ cr_) << 4));     \
    D1 = *(const bf16x8_t*)(rp_ + (((((kk) + 1) * 4 + lhi) ^ cr_) << 4));     \
  } while (0)

#define CL2(S0, S1, kk) do {                                                  \
    __builtin_amdgcn_s_setprio(1);                                            \
    acc0 = __builtin_amdgcn_mfma_f32_16x16x32_bf16(afa[kk],     S0, acc0, 0, 0, 0); \
    acc1 = __builtin_amdgcn_mfma_f32_16x16x32_bf16(afb[kk],     S0, acc1, 0, 0, 0); \
    acc0 = __builtin_amdgcn_mfma_f32_16x16x32_bf16(afa[kk + 1], S1, acc0, 0, 0, 0); \
    acc1 = __builtin_amdgcn_mfma_f32_16x16x32_bf16(afb[kk + 1], S1, acc1, 0, 0, 0); \
    __builtin_amdgcn_s_setprio(0);                                            \
  } while (0)

#define EPI(ntv) do {                                                         \
    const int gc_ = cb + (ntv) * 16 + llo;                                    \
    if (has_diag) {                                                           \
      _Pragma("unroll")                                                       \
      for (int j = 0; j < 4; ++j) {                                           \
        racc0[j] += ((gr0 + j) != gc_) ? EXP2F(acc0[j]) : 0.f;                \
        racc1[j] += ((gr1 + j) != gc_) ? EXP2F(acc1[j]) : 0.f;                \
      }                                                                       \
    } else {                                                                  \
      _Pragma("unroll")                                                       \
      for (int j = 0; j < 4; ++j) {                                           \
        racc0[j] += EXP2F(acc0[j]);                                           \
        racc1[j] += EXP2F(acc1[j]);                                           \
      }                                                                       \
    }                                                                         \
    acc0 = (f32x4_t){0.f, 0.f, 0.f, 0.f};                                     \
    acc1 = (f32x4_t){0.f, 0.f, 0.f, 0.f};                                     \
  } while (0)

  // Tile body: straight-line 8-batch pipeline. Each LDB2 (2 ds_read_b128) is
  // issued BEFORE the MFMA cluster consuming the PREVIOUS batch -> DS latency
  // hides under MFMA; compiler emits counted lgkmcnt automatically.
#define TILE(ct_, VMSTR) do {                                                 \
    asm volatile("s_waitcnt " VMSTR ::: "memory");                            \
    __syncthreads();                                                          \
    const int cb = c0 + (ct_) * BN;                                           \
    const short* bufp = smem[(ct_) & 3];                                      \
    if ((ct_) + 3 < NT) {                                                     \
      STAGE1(((ct_) + 3) & 3, (ct_) + 3, 0);                                  \
      STAGE1(((ct_) + 3) & 3, (ct_) + 3, 1);                                  \
    }                                                                         \
    LDB2(u0, u1, 0, 0);                                                       \
    LDB2(v0, v1, 0, 2);  CL2(u0, u1, 0);                                      \
    LDB2(u0, u1, 0, 4);  CL2(v0, v1, 2);                                      \
    LDB2(v0, v1, 0, 6);  CL2(u0, u1, 4);                                      \
    LDB2(u0, u1, 1, 0);  CL2(v0, v1, 6);                                      \
    LDB2(v0, v1, 1, 2);  EPI(0);  CL2(u0, u1, 0);                             \
    LDB2(u0, u1, 1, 4);  CL2(v0, v1, 2);                                      \
    LDB2(v0, v1, 1, 6);  CL2(u0, u1, 4);                                      \
    CL2(v0, v1, 6);                                                           \
    EPI(1);                                                                   \
  } while (0)

  // Prologue: prefetch tiles 0,1,2 (6 loads/thread in flight).
  #pragma unroll
  for (int t = 0; t < 3; ++t) {
    STAGE1(t, t, 0);
    STAGE1(t, t, 1);
  }

  for (int ct = 0; ct < NT - 2; ++ct) TILE(ct, "vmcnt(4)");
  TILE(NT - 2, "vmcnt(2)");
  TILE(NT - 1, "vmcnt(0)");
#undef TILE
#undef EPI
#undef CL2
#undef LDB2
#undef STAGE1

  // Per-row partial sums -> global rowsum (16 adds per row address total).
  #pragma unroll
  for (int j = 0; j < 4; ++j) {
    float p0 = racc0[j], p1 = racc1[j];
    p0 += __shfl_xor(p0, 1, 16); p1 += __shfl_xor(p1, 1, 16);
    p0 += __shfl_xor(p0, 2, 16); p1 += __shfl_xor(p1, 2, 16);
    p0 += __shfl_xor(p0, 4, 16); p1 += __shfl_xor(p1, 4, 16);
    p0 += __shfl_xor(p0, 8, 16); p1 += __shfl_xor(p1, 8, 16);
    if (llo == 0) {
      atomicAdd(&rowsum[gr0 + j], p0);
      atomicAdd(&rowsum[gr1 + j], p1);
    }
  }
}

// ------- K3: loss = (sum_r log(rowsum_r) - 2*sum_i rowdiag_i) / 2n -------
__global__ __launch_bounds__(256) void finalize_kernel(
    const float* __restrict__ rowsum, const float* __restrict__ rowdiag,
    float* __restrict__ out) {
  const int t = threadIdx.x;
  float s = 0.f;
  for (int r4 = t; r4 < NROWS / 4; r4 += 256) {
    const float4 v = ((const float4*)rowsum)[r4];
    s += __logf(v.x) + __logf(v.y) + __logf(v.z) + __logf(v.w);
  }
  for (int i4 = t; i4 < 4096 / 4; i4 += 256) {
    const float4 d = ((const float4*)rowdiag)[i4];
    s -= 2.0f * (d.x + d.y + d.z + d.w);
  }
  #pragma unroll
  for (int off = 32; off > 0; off >>= 1) s += __shfl_xor(s, off, 64);
  __shared__ float wsum[4];
  const int w = t >> 6, lane = t & 63;
  if (lane == 0) wsum[w] = s;
  __syncthreads();
  if (t == 0) out[0] = (wsum[0] + wsum[1] + wsum[2] + wsum[3]) / (float)NROWS;
}

extern "C" void kernel_launch(void* const* d_in, const int* in_sizes, int n_in,
                              void* d_out, int out_size, void* d_ws, size_t ws_size,
                              hipStream_t stream) {
  const float* x = (const float*)d_in[0];
  const float* y = (const float*)d_in[1];
  float* out = (float*)d_out;

  char* ws = (char*)d_ws;
  __hip_bfloat16* zb = (__hip_bfloat16*)ws;                       // 4 MB
  float* rowsum  = (float*)(ws + (size_t)NROWS * DDIM * 2);       // 32 KB
  float* rowdiag = rowsum + NROWS;                                // 16 KB

  normalize_diag_kernel<<<1024, 256, 0, stream>>>(x, y, zb, rowdiag, rowsum);
  gram_lse_kernel<<<512, 512, 0, stream>>>(zb, rowsum);
  finalize_kernel<<<1, 256, 0, stream>>>(rowsum, rowdiag, out);
}

// Round 11
// 78.817 us; speedup vs baseline: 1.0308x; 1.0308x over previous
//
#include <hip/hip_runtime.h>
#include <hip/hip_bf16.h>

// InfoNCE loss, N=4096, D=256, tau=0.5.
// loss = (1/2n)[ sum_r log(sum_{k!=r} exp(2*Z_r.Z_k)) - 2*sum_i 2*(xn_i.yn_i) ]
// Z = concat(xn, yn) row-normalized; scores in [-2,2] -> no running max needed.
// 2/tau*log2(e) folded into A-side bf16 fragments; epilogue = exp2 + add.
//
// R11: SYMMETRY. G is symmetric -> compute only the lower triangle in 128x256
// tiles (1056 blocks); each exp(s_rc) with r>c contributes to rowsum[r]
// (row side, as before) AND rowsum[c] (col side: in-reg j-sum + shfl 16/32 +
// LDS ds_add into colacc[256], flushed once per block). Inner loop = R3's
// proven R=1 structure (8 waves x 16 rows, BN=64, ~52 VGPR, single-buffer
// 32KB + 1KB colacc = 33792B LDS). All pipes halve vs R3 (LDS 41->21us,
// MFMA 16.6->8.5, exp 14->7). R4-R10 lesson: R=2 reuse spills or halves
// occupancy -- abandoned.

#define NROWS 8192
#define DDIM  256
#define BM    128        // rows per block = 8 waves * 16 rows
#define BN    64         // cols per LDS tile (32 KB)
#define COLS_PER 256     // cols per block
#define NT (COLS_PER / BN)            // 4 tiles
#define NBLK 1056        // sum_{J=0}^{31} (64 - 2J)

typedef __attribute__((ext_vector_type(8))) __bf16 bf16x8_t;
typedef __attribute__((ext_vector_type(4))) float  f32x4_t;

typedef __attribute__((address_space(1))) const void* as1_cvp;
typedef __attribute__((address_space(3))) void*       as3_vp;

#if __has_builtin(__builtin_amdgcn_exp2f)
#define EXP2F __builtin_amdgcn_exp2f
#else
#define EXP2F exp2f
#endif

#define TWO_LOG2E 2.8853900817779268f

// ---- K1: normalize rows + per-pair diag dot + zero rowsum ----
__global__ __launch_bounds__(256) void normalize_diag_kernel(
    const float* __restrict__ x, const float* __restrict__ y,
    __hip_bfloat16* __restrict__ zb, float* __restrict__ rowdiag,
    float* __restrict__ rowsum) {
  const int g = blockIdx.x * 256 + threadIdx.x;
  if (g < NROWS) rowsum[g] = 0.f;

  const int w = threadIdx.x >> 6, lane = threadIdx.x & 63;
  const int i = blockIdx.x * 4 + w;           // 0..4095
  const float4 xv = ((const float4*)(x + (size_t)i * DDIM))[lane];
  const float4 yv = ((const float4*)(y + (size_t)i * DDIM))[lane];
  float ssx = xv.x * xv.x + xv.y * xv.y + xv.z * xv.z + xv.w * xv.w;
  float ssy = yv.x * yv.x + yv.y * yv.y + yv.z * yv.z + yv.w * yv.w;
  float sxy = xv.x * yv.x + xv.y * yv.y + xv.z * yv.z + xv.w * yv.w;
  #pragma unroll
  for (int off = 32; off > 0; off >>= 1) {
    ssx += __shfl_xor(ssx, off, 64);
    ssy += __shfl_xor(ssy, off, 64);
    sxy += __shfl_xor(sxy, off, 64);
  }
  const float sclx = 1.0f / fmaxf(sqrtf(ssx), 1e-8f);
  const float scly = 1.0f / fmaxf(sqrtf(ssy), 1e-8f);
  __hip_bfloat16 px[4], py[4];
  px[0] = __float2bfloat16(xv.x * sclx); px[1] = __float2bfloat16(xv.y * sclx);
  px[2] = __float2bfloat16(xv.z * sclx); px[3] = __float2bfloat16(xv.w * sclx);
  py[0] = __float2bfloat16(yv.x * scly); py[1] = __float2bfloat16(yv.y * scly);
  py[2] = __float2bfloat16(yv.z * scly); py[3] = __float2bfloat16(yv.w * scly);
  *(short4*)(zb + (size_t)i * DDIM + lane * 4)            = *(short4*)px;
  *(short4*)(zb + (size_t)(i + 4096) * DDIM + lane * 4)   = *(short4*)py;
  if (lane == 0) rowdiag[i] = 2.0f * sxy * sclx * scly;   // target score (f32)
}

// ---- K2: lower-triangle Gram + two-sided sum of exp ----
__global__ __launch_bounds__(512) void gram_lse_kernel(
    const __hip_bfloat16* __restrict__ zbh, float* __restrict__ rowsum) {
  __shared__ short smem[BN * DDIM];    // 32 KB single buffer
  __shared__ float colacc[COLS_PER];   // 1 KB col-side accumulator

  const short* zs = (const short*)zbh;
  const char* zbytes = (const char*)zs;
  const int tid  = threadIdx.x;
  const int w    = tid >> 6;    // 0..7
  const int lane = tid & 63;
  const int lhi  = lane >> 4;   // 0..3
  const int llo  = lane & 15;   // 0..15

  // Block -> (I, J) over the lower triangle: J col-chunk (256 wide),
  // I row-tile (128 tall), needed iff I >= 2J; count per J = 64 - 2J.
  int jj = 0, rem = blockIdx.x;
  while (rem >= 64 - 2 * jj) { rem -= 64 - 2 * jj; ++jj; }
  const int I = 2 * jj + rem;
  const int i0 = I * BM;
  const int c0 = jj * COLS_PER;
  const bool straddle = (rem <= 1);   // tile touches the diagonal

  if (tid < COLS_PER) colacc[tid] = 0.f;

  // A fragments: 16 rows per wave, full K=256, pre-scaled by bf16(2*log2e).
  const int arow = i0 + w * 16 + llo;
  const float TBF = __bfloat162float(__float2bfloat16(TWO_LOG2E));
  bf16x8_t afrag[8];
  #pragma unroll
  for (int ks = 0; ks < 8; ++ks) {
    afrag[ks] = *(const bf16x8_t*)(zs + (size_t)arow * DDIM + ks * 32 + lhi * 8);
    #pragma unroll
    for (int e = 0; e < 8; ++e)
      afrag[ks][e] = (__bf16)((float)afrag[ks][e] * TBF);
  }

  // Staging: 512 threads x 16 B x 4 rounds = 32 KB tile. Linear LDS dest
  // (wave-uniform base + lane*16), XOR-swizzle applied on the global source:
  //   lds[cr*512 + slot*16 .. +16) = row (cb+cr) bytes [(slot ^ (cr&31))*16 ..)
  int soff[4], loff[4];
  #pragma unroll
  for (int it = 0; it < 4; ++it) {
    const int o    = it * 8192 + tid * 16;
    const int cr   = o >> 9;            // 0..63
    const int slot = (o >> 4) & 31;
    soff[it] = cr * 512 + ((slot ^ (cr & 31)) << 4);
    loff[it] = it * 8192 + w * 1024;    // wave-uniform dest base
  }

  float racc[4] = {0.f, 0.f, 0.f, 0.f};
  const int gr0 = i0 + w * 16 + lhi * 4;   // C/D row = (lane>>4)*4 + j

  for (int ct = 0; ct < NT; ++ct) {
    __syncthreads();                       // previous tile's reads done
    {
      const size_t cbase = (size_t)(c0 + ct * BN) * 512;
      #pragma unroll
      for (int it = 0; it < 4; ++it) {
        __builtin_amdgcn_global_load_lds(
            (as1_cvp)(zbytes + cbase + (size_t)soff[it]),
            (as3_vp)((char*)smem + loff[it]), 16, 0, 0);
      }
    }
    asm volatile("s_waitcnt vmcnt(0)" ::: "memory");
    __syncthreads();

    #pragma unroll
    for (int nt = 0; nt < 4; ++nt) {
      const int cr = nt * 16 + llo;      // key (column) this lane feeds as B
      f32x4_t acc = {0.f, 0.f, 0.f, 0.f};
      #pragma unroll
      for (int ks = 0; ks < 8; ++ks) {
        const int kg = ks * 4 + lhi;     // 16B k-slot
        const bf16x8_t bfrag = *(const bf16x8_t*)(
            (const char*)smem + cr * 512 + ((kg ^ (cr & 31)) << 4));
        acc = __builtin_amdgcn_mfma_f32_16x16x32_bf16(afrag[ks], bfrag, acc, 0, 0, 0);
      }
      const int gc = c0 + ct * BN + cr;
      float e[4];
      #pragma unroll
      for (int j = 0; j < 4; ++j) e[j] = EXP2F(acc[j]);
      if (straddle) {                    // keep strictly-lower only
        #pragma unroll
        for (int j = 0; j < 4; ++j) e[j] = ((gr0 + j) > gc) ? e[j] : 0.f;
      }
      #pragma unroll
      for (int j = 0; j < 4; ++j) racc[j] += e[j];   // row side
      // col side: sum over the 16 rows of this fragment
      float cs = (e[0] + e[1]) + (e[2] + e[3]);
      cs += __shfl_xor(cs, 16, 64);
      cs += __shfl_xor(cs, 32, 64);
      if (lane < 16) atomicAdd(&colacc[ct * BN + cr], cs);
    }
  }

  // Row-side flush: reduce across the 16 lanes holding each row's columns.
  #pragma unroll
  for (int j = 0; j < 4; ++j) {
    float v = racc[j];
    v += __shfl_xor(v, 1, 16);
    v += __shfl_xor(v, 2, 16);
    v += __shfl_xor(v, 4, 16);
    v += __shfl_xor(v, 8, 16);
    if (llo == 0) atomicAdd(&rowsum[gr0 + j], v);
  }

  // Col-side flush: one atomic per column per block.
  __syncthreads();
  if (tid < COLS_PER) atomicAdd(&rowsum[c0 + tid], colacc[tid]);
}

// ------- K3: loss = (sum_r log(rowsum_r) - 2*sum_i rowdiag_i) / 2n -------
__global__ __launch_bounds__(256) void finalize_kernel(
    const float* __restrict__ rowsum, const float* __restrict__ rowdiag,
    float* __restrict__ out) {
  const int t = threadIdx.x;
  float s = 0.f;
  for (int r4 = t; r4 < NROWS / 4; r4 += 256) {
    const float4 v = ((const float4*)rowsum)[r4];
    s += __logf(v.x) + __logf(v.y) + __logf(v.z) + __logf(v.w);
  }
  for (int i4 = t; i4 < 4096 / 4; i4 += 256) {
    const float4 d = ((const float4*)rowdiag)[i4];
    s -= 2.0f * (d.x + d.y + d.z + d.w);
  }
  #pragma unroll
  for (int off = 32; off > 0; off >>= 1) s += __shfl_xor(s, off, 64);
  __shared__ float wsum[4];
  const int w = t >> 6, lane = t & 63;
  if (lane == 0) wsum[w] = s;
  __syncthreads();
  if (t == 0) out[0] = (wsum[0] + wsum[1] + wsum[2] + wsum[3]) / (float)NROWS;
}

extern "C" void kernel_launch(void* const* d_in, const int* in_sizes, int n_in,
                              void* d_out, int out_size, void* d_ws, size_t ws_size,
                              hipStream_t stream) {
  const float* x = (const float*)d_in[0];
  const float* y = (const float*)d_in[1];
  float* out = (float*)d_out;

  char* ws = (char*)d_ws;
  __hip_bfloat16* zb = (__hip_bfloat16*)ws;                       // 4 MB
  float* rowsum  = (float*)(ws + (size_t)NROWS * DDIM * 2);       // 32 KB
  float* rowdiag = rowsum + NROWS;                                // 16 KB

  normalize_diag_kernel<<<1024, 256, 0, stream>>>(x, y, zb, rowdiag, rowsum);
  gram_lse_kernel<<<NBLK, 512, 0, stream>>>(zb, rowsum);
  finalize_kernel<<<1, 256, 0, stream>>>(rowsum, rowdiag, out);
}

// Round 12
// 57.457 us; speedup vs baseline: 1.4139x; 1.3718x over previous
//
#include <hip/hip_runtime.h>
#include <hip/hip_bf16.h>

// InfoNCE loss, N=4096, D=256, tau=0.5.
// loss = (1/2n)[ sum_r log(sum_{k!=r} exp(2*Z_r.Z_k)) - 2*sum_i 2*(xn_i.yn_i) ]
// Z = concat(xn, yn) row-normalized; scores in [-2,2] -> no running max needed.
// 2/tau*log2(e) folded into A-side bf16 fragments; epilogue = exp2 + add.
//
// R12: symmetry INSIDE R3's exact proven shell. G is symmetric: compute only
// strictly-lower-triangle blocks (128 rows x 512 cols, I >= 4J, 544 blocks);
// each exp feeds rowsum[r] (row side, unchanged) and rowsum[c] (col side:
// 3 adds + 2 shfl + NON-atomic LDS colpart write, double-buffered; reduced
// post-barrier by 64 threads -> 1 global atomic per column per tile).
// R11 lesson: keep the dbuf prefetch pipeline + BN=64 + 8-wave blocks intact.

#define NROWS 8192
#define DDIM  256
#define BM    128        // rows per block = 8 waves * 16 rows
#define BN    64         // cols per LDS tile (32 KB)
#define COLS_PER 512     // cols per block
#define NT (COLS_PER / BN)   // 8 tiles
#define NBLK 544         // sum_{J=0}^{15} (64 - 4J)

typedef __attribute__((ext_vector_type(8))) __bf16 bf16x8_t;
typedef __attribute__((ext_vector_type(4))) float  f32x4_t;

typedef __attribute__((address_space(1))) const void* as1_cvp;
typedef __attribute__((address_space(3))) void*       as3_vp;

#if __has_builtin(__builtin_amdgcn_exp2f)
#define EXP2F __builtin_amdgcn_exp2f
#else
#define EXP2F exp2f
#endif

#define TWO_LOG2E 2.8853900817779268f

// ---- K1: normalize rows + per-pair diag dot + zero rowsum ----
__global__ __launch_bounds__(256) void normalize_diag_kernel(
    const float* __restrict__ x, const float* __restrict__ y,
    __hip_bfloat16* __restrict__ zb, float* __restrict__ rowdiag,
    float* __restrict__ rowsum) {
  const int g = blockIdx.x * 256 + threadIdx.x;
  if (g < NROWS) rowsum[g] = 0.f;

  const int w = threadIdx.x >> 6, lane = threadIdx.x & 63;
  const int i = blockIdx.x * 4 + w;           // 0..4095
  const float4 xv = ((const float4*)(x + (size_t)i * DDIM))[lane];
  const float4 yv = ((const float4*)(y + (size_t)i * DDIM))[lane];
  float ssx = xv.x * xv.x + xv.y * xv.y + xv.z * xv.z + xv.w * xv.w;
  float ssy = yv.x * yv.x + yv.y * yv.y + yv.z * yv.z + yv.w * yv.w;
  float sxy = xv.x * yv.x + xv.y * yv.y + xv.z * yv.z + xv.w * yv.w;
  #pragma unroll
  for (int off = 32; off > 0; off >>= 1) {
    ssx += __shfl_xor(ssx, off, 64);
    ssy += __shfl_xor(ssy, off, 64);
    sxy += __shfl_xor(sxy, off, 64);
  }
  const float sclx = 1.0f / fmaxf(sqrtf(ssx), 1e-8f);
  const float scly = 1.0f / fmaxf(sqrtf(ssy), 1e-8f);
  __hip_bfloat16 px[4], py[4];
  px[0] = __float2bfloat16(xv.x * sclx); px[1] = __float2bfloat16(xv.y * sclx);
  px[2] = __float2bfloat16(xv.z * sclx); px[3] = __float2bfloat16(xv.w * sclx);
  py[0] = __float2bfloat16(yv.x * scly); py[1] = __float2bfloat16(yv.y * scly);
  py[2] = __float2bfloat16(yv.z * scly); py[3] = __float2bfloat16(yv.w * scly);
  *(short4*)(zb + (size_t)i * DDIM + lane * 4)            = *(short4*)px;
  *(short4*)(zb + (size_t)(i + 4096) * DDIM + lane * 4)   = *(short4*)py;
  if (lane == 0) rowdiag[i] = 2.0f * sxy * sclx * scly;   // target score (f32)
}

// ---- K2: strictly-lower-triangle Gram + two-sided sum of exp ----
__global__ __launch_bounds__(512) void gram_lse_kernel(
    const __hip_bfloat16* __restrict__ zbh, float* __restrict__ rowsum) {
  __shared__ short smem[2][BN * DDIM];     // 64 KB double buffer (as R3)
  __shared__ float colpart[2][8][BN];      // 4 KB, dbuf'd by ct&1 (non-atomic)

  const short* zs = (const short*)zbh;
  const char* zbytes = (const char*)zs;
  const int tid  = threadIdx.x;
  const int w    = tid >> 6;    // 0..7
  const int lane = tid & 63;
  const int lhi  = lane >> 4;   // 0..3
  const int llo  = lane & 15;   // 0..15

  // Block -> (J, I) over the strictly-lower triangle. Col chunk J (512 wide),
  // row tile I (128 tall); included iff I >= 4J; count per J = 64 - 4J.
  int jj = 0, rem = blockIdx.x;
  while (rem >= 64 - 4 * jj) { rem -= 64 - 4 * jj; ++jj; }
  const int I = 4 * jj + rem;
  const int i0 = I * BM;
  const int c0 = jj * COLS_PER;
  const bool straddle = (rem <= 3);   // diagonal crosses this block

  // A fragments: 16 rows per wave, full K=256, pre-scaled by bf16(2*log2e).
  const int arow = i0 + w * 16 + llo;
  const float TBF = __bfloat162float(__float2bfloat16(TWO_LOG2E));
  bf16x8_t afrag[8];
  #pragma unroll
  for (int ks = 0; ks < 8; ++ks) {
    afrag[ks] = *(const bf16x8_t*)(zs + (size_t)arow * DDIM + ks * 32 + lhi * 8);
    #pragma unroll
    for (int e = 0; e < 8; ++e)
      afrag[ks][e] = (__bf16)((float)afrag[ks][e] * TBF);
  }

  // Staging offsets (exactly R3): 512 thr x 16 B x 4 = 32 KB tile; linear LDS
  // dest, XOR-swizzle on the global source.
  int soff[4], loff[4];
  #pragma unroll
  for (int it = 0; it < 4; ++it) {
    const int o    = it * 8192 + tid * 16;
    const int cr   = o >> 9;            // 0..63
    const int slot = (o >> 4) & 31;
    soff[it] = cr * 512 + ((slot ^ (cr & 31)) << 4);
    loff[it] = it * 8192 + w * 1024;    // wave-uniform dest base
  }

#define STAGE(buf, ct_) do {                                                  \
    const size_t cbase = (size_t)(c0 + (ct_) * BN) * 512;                     \
    _Pragma("unroll")                                                         \
    for (int it = 0; it < 4; ++it) {                                          \
      __builtin_amdgcn_global_load_lds(                                       \
          (as1_cvp)(zbytes + cbase + (size_t)soff[it]),                       \
          (as3_vp)((char*)smem[buf] + loff[it]), 16, 0, 0);                   \
    }                                                                         \
  } while (0)

  float racc[4] = {0.f, 0.f, 0.f, 0.f};
  const int gr0 = i0 + w * 16 + lhi * 4;   // C/D row = (lane>>4)*4 + j

  STAGE(0, 0);
  asm volatile("s_waitcnt vmcnt(0)" ::: "memory");
  __syncthreads();
  int cur = 0;

  for (int ct = 0; ct < NT; ++ct) {
    if (ct + 1 < NT) STAGE(cur ^ 1, ct + 1);   // prefetch overlaps compute
    const int cb = c0 + ct * BN;

    #pragma unroll
    for (int nt = 0; nt < 4; ++nt) {
      const int cr = nt * 16 + llo;      // key (column) this lane feeds as B
      f32x4_t acc = {0.f, 0.f, 0.f, 0.f};
      #pragma unroll
      for (int ks = 0; ks < 8; ++ks) {
        const int kg = ks * 4 + lhi;     // 16B k-slot
        const bf16x8_t bfrag = *(const bf16x8_t*)(
            (const char*)smem[cur] + cr * 512 + ((kg ^ (cr & 31)) << 4));
        acc = __builtin_amdgcn_mfma_f32_16x16x32_bf16(afrag[ks], bfrag, acc, 0, 0, 0);
      }
      float e[4];
      #pragma unroll
      for (int j = 0; j < 4; ++j) e[j] = EXP2F(acc[j]);
      if (straddle) {                    // keep strictly-lower only (kills diag)
        const int gc = cb + cr;
        #pragma unroll
        for (int j = 0; j < 4; ++j) e[j] = ((gr0 + j) > gc) ? e[j] : 0.f;
      }
      #pragma unroll
      for (int j = 0; j < 4; ++j) racc[j] += e[j];       // row side
      // col side: sum this fragment's 4 rows, then the wave's 4 lhi groups.
      float cs = (e[0] + e[1]) + (e[2] + e[3]);
      cs += __shfl_xor(cs, 16, 64);
      cs += __shfl_xor(cs, 32, 64);
      if (lane < 16) colpart[ct & 1][w][nt * 16 + llo] = cs;  // non-atomic
    }
    asm volatile("s_waitcnt vmcnt(0)" ::: "memory");  // prefetched tile landed
    __syncthreads();
    // Col-side reduce for tile ct (reads colpart[ct&1]; slot reused only at
    // ct+2, which is ordered behind the barrier at end of tile ct+1).
    if (tid < BN) {
      float s = 0.f;
      #pragma unroll
      for (int ww = 0; ww < 8; ++ww) s += colpart[ct & 1][ww][tid];
      atomicAdd(&rowsum[cb + tid], s);
    }
    cur ^= 1;
  }
#undef STAGE

  // Row-side flush: reduce across the 16 lanes holding each row's columns.
  #pragma unroll
  for (int j = 0; j < 4; ++j) {
    float v = racc[j];
    v += __shfl_xor(v, 1, 16);
    v += __shfl_xor(v, 2, 16);
    v += __shfl_xor(v, 4, 16);
    v += __shfl_xor(v, 8, 16);
    if (llo == 0) atomicAdd(&rowsum[gr0 + j], v);
  }
}

// ------- K3: loss = (sum_r log(rowsum_r) - 2*sum_i rowdiag_i) / 2n -------
__global__ __launch_bounds__(256) void finalize_kernel(
    const float* __restrict__ rowsum, const float* __restrict__ rowdiag,
    float* __restrict__ out) {
  const int t = threadIdx.x;
  float s = 0.f;
  for (int r4 = t; r4 < NROWS / 4; r4 += 256) {
    const float4 v = ((const float4*)rowsum)[r4];
    s += __logf(v.x) + __logf(v.y) + __logf(v.z) + __logf(v.w);
  }
  for (int i4 = t; i4 < 4096 / 4; i4 += 256) {
    const float4 d = ((const float4*)rowdiag)[i4];
    s -= 2.0f * (d.x + d.y + d.z + d.w);
  }
  #pragma unroll
  for (int off = 32; off > 0; off >>= 1) s += __shfl_xor(s, off, 64);
  __shared__ float wsum[4];
  const int w = t >> 6, lane = t & 63;
  if (lane == 0) wsum[w] = s;
  __syncthreads();
  if (t == 0) out[0] = (wsum[0] + wsum[1] + wsum[2] + wsum[3]) / (float)NROWS;
}

extern "C" void kernel_launch(void* const* d_in, const int* in_sizes, int n_in,
                              void* d_out, int out_size, void* d_ws, size_t ws_size,
                              hipStream_t stream) {
  const float* x = (const float*)d_in[0];
  const float* y = (const float*)d_in[1];
  float* out = (float*)d_out;

  char* ws = (char*)d_ws;
  __hip_bfloat16* zb = (__hip_bfloat16*)ws;                       // 4 MB
  float* rowsum  = (float*)(ws + (size_t)NROWS * DDIM * 2);       // 32 KB
  float* rowdiag = rowsum + NROWS;                                // 16 KB

  normalize_diag_kernel<<<1024, 256, 0, stream>>>(x, y, zb, rowdiag, rowsum);
  gram_lse_kernel<<<NBLK, 512, 0, stream>>>(zb, rowsum);
  finalize_kernel<<<1, 256, 0, stream>>>(rowsum, rowdiag, out);
}